// Round 1
// baseline (724.430 us; speedup 1.0000x reference)
//
#include <hip/hip_runtime.h>
#include <cmath>
#include <complex>
#include <algorithm>

// ======================================================================
// Host-side exact port of the reference e3nn wigner_3j (unit Frobenius
// norm, real basis, (-1j)^l phase). Computed once on host, passed to the
// kernel BY VALUE (kernarg segment -> s_load), alpha pre-folded.
// ======================================================================

typedef std::complex<double> cd;

static double factd(int n) { double r = 1; for (int i = 2; i <= n; ++i) r *= i; return r; }

static double su2_cg(int j1, int m1, int j2, int m2, int j3, int m3) {
    if (m3 != m1 + m2) return 0.0;
    int vmin = std::max(std::max(-j1 + j2 + m3, -j1 + m1), 0);
    int vmax = std::min(std::min(j2 + j3 + m1, j3 - j1 + j2), j3 + m3);
    double C = std::sqrt((2.0 * j3 + 1.0) *
        (factd(j3 + j1 - j2) * factd(j3 - j1 + j2) * factd(j1 + j2 - j3) *
         factd(j3 + m3) * factd(j3 - m3)) /
        (factd(j1 + j2 + j3 + 1) * factd(j1 - m1) * factd(j1 + m1) *
         factd(j2 - m2) * factd(j2 + m2)));
    double S = 0.0;
    for (int v = vmin; v <= vmax; ++v) {
        double sgn = ((v + j2 + m2) & 1) ? -1.0 : 1.0;
        S += sgn * (factd(j2 + j3 + m1 - v) * factd(j1 - m1 + v)) /
             (factd(v) * factd(j3 - j1 + j2 - v) * factd(j3 + m3 - v) *
              factd(v + j1 - j2 - m3));
    }
    return C * S;
}

static void qmat(int l, cd* q) {  // (2l+1)x(2l+1), row-major
    int n = 2 * l + 1;
    for (int i = 0; i < n * n; ++i) q[i] = cd(0, 0);
    const double s = 1.0 / std::sqrt(2.0);
    for (int m = -l; m < 0; ++m) {
        q[(l + m) * n + (l - m)] = cd(s, 0);    // col l+|m|
        q[(l + m) * n + (l + m)] = cd(0, -s);   // col l-|m|
    }
    q[l * n + l] = cd(1, 0);
    for (int m = 1; m <= l; ++m) {
        double sg = (m & 1) ? -1.0 : 1.0;
        q[(l + m) * n + (l + m)] = cd(sg * s, 0);
        q[(l + m) * n + (l - m)] = cd(0, sg * s);
    }
    cd ph(1, 0);
    for (int t = 0; t < l; ++t) ph *= cd(0, -1);  // (-1j)^l
    for (int i = 0; i < n * n; ++i) q[i] *= ph;
}

static void wigner3j_dense(int l1, int l2, int l3, float* outp) {
    int n1 = 2 * l1 + 1, n2 = 2 * l2 + 1, n3 = 2 * l3 + 1;
    double cg[125];
    for (int i = 0; i < n1 * n2 * n3; ++i) cg[i] = 0.0;
    for (int m1 = -l1; m1 <= l1; ++m1)
        for (int m2 = -l2; m2 <= l2; ++m2) {
            int m3 = m1 + m2;
            if (std::abs(m3) <= l3)
                cg[((l1 + m1) * n2 + (l2 + m2)) * n3 + (l3 + m3)] =
                    su2_cg(l1, m1, l2, m2, l3, m3);
        }
    cd q1[25], q2[25], q3[25];
    qmat(l1, q1); qmat(l2, q2); qmat(l3, q3);
    // out[j,l,m] = Re( sum_{i,k,n} q1[i,j] q2[k,l] conj(q3[n,m]) cg[i,k,n] )
    double C[125]; double norm2 = 0.0;
    for (int j = 0; j < n1; ++j)
        for (int l = 0; l < n2; ++l)
            for (int m = 0; m < n3; ++m) {
                cd sum(0, 0);
                for (int i = 0; i < n1; ++i)
                    for (int k = 0; k < n2; ++k)
                        for (int n = 0; n < n3; ++n) {
                            double g = cg[(i * n2 + k) * n3 + n];
                            if (g != 0.0)
                                sum += q1[i * n1 + j] * q2[k * n2 + l] *
                                       std::conj(q3[n * n3 + m]) * g;
                        }
                C[(j * n2 + l) * n3 + m] = sum.real();
                norm2 += sum.real() * sum.real();
            }
    double inv = 1.0 / std::sqrt(norm2);
    for (int t = 0; t < n1 * n2 * n3; ++t) outp[t] = (float)(C[t] * inv);
}

struct W3JArg { float c[363]; };  // 11 dense path tensors, alpha folded in

static W3JArg build_w3j() {
    W3JArg arg;
    struct P { int l1, l2, lo, coff; double alpha; };
    // alpha = sqrt((2*lo+1) / (paths_to_io * 32 * 32)); counts: io0=3, io1=4, io2=4
    const P ps[11] = {
        {0,0,0,   0, std::sqrt(1.0/3072.0)},
        {1,1,0,   1, std::sqrt(1.0/3072.0)},
        {2,2,0,  10, std::sqrt(1.0/3072.0)},
        {0,1,1,  35, std::sqrt(3.0/4096.0)},
        {1,0,1,  44, std::sqrt(3.0/4096.0)},
        {1,2,1,  53, std::sqrt(3.0/4096.0)},
        {2,1,1,  98, std::sqrt(3.0/4096.0)},
        {0,2,2, 143, std::sqrt(5.0/4096.0)},
        {1,1,2, 168, std::sqrt(5.0/4096.0)},
        {2,0,2, 213, std::sqrt(5.0/4096.0)},
        {2,2,2, 238, std::sqrt(5.0/4096.0)}
    };
    for (int pi = 0; pi < 11; ++pi) {
        const P& p = ps[pi];
        float tmp[125];
        wigner3j_dense(p.l1, p.l2, p.lo, tmp);
        int n = (2*p.l1+1) * (2*p.l2+1) * (2*p.lo+1);
        for (int t = 0; t < n; ++t) arg.c[p.coff + t] = (float)(tmp[t] * p.alpha);
    }
    return arg;
}

// ======================================================================
// Device kernel
//   block = 256 threads = 4 u-quarters x 2 z x 32 lanes; grid = B/2
//   per u-step: T phase (thread = (q,zg,v) computes 35 T slots -> LDS),
//               main phase (thread = (q,zg,w) accumulates over v)
// ======================================================================

#define NSLOT 36  // 35 used slots, padded to 36 for float4 + bank offset

// slot base / out-components per path
static constexpr int SLOT_OF[11] = {0, 1, 2, 3, 6, 9, 12, 15, 20, 25, 30};
static constexpr int D3_OF[11]   = {1, 1, 1, 3, 3, 3, 3, 5, 5, 5, 5};

template<int L1, int L2, int LO, int COFF, int SLOT>
__device__ __forceinline__ void t_path(const float* __restrict__ c,
                                       const float* a, const float* b, float* t) {
    constexpr int D1 = 2 * L1 + 1, D2 = 2 * L2 + 1, D3 = 2 * LO + 1;
    constexpr int A1 = (L1 == 0) ? 0 : (L1 == 1) ? 1 : 4;
    constexpr int A2 = (L2 == 0) ? 0 : (L2 == 1) ? 1 : 4;
    #pragma unroll
    for (int i = 0; i < D1; ++i)
        #pragma unroll
        for (int j = 0; j < D2; ++j) {
            float prod = a[A1 + i] * b[A2 + j];
            #pragma unroll
            for (int k = 0; k < D3; ++k)
                t[SLOT + k] = fmaf(c[COFF + (i * D2 + j) * D3 + k], prod, t[SLOT + k]);
        }
}

__launch_bounds__(256, 3)
__global__ void tp_kernel(const float* __restrict__ x1,
                          const float* __restrict__ x2,
                          const float* __restrict__ ws,
                          float* __restrict__ out,
                          W3JArg w3j) {
    __shared__ float ldsT[256 * NSLOT];   // T rows / partial-acc rows
    __shared__ float x1s[576];            // 2 z * 288
    __shared__ float x2s[576];

    const int tid = threadIdx.x;
    const int lw  = tid & 31;          // v in T phase, w in main phase
    const int zg  = (tid >> 5) & 1;
    const int q   = tid >> 6;          // u-quarter
    const int z0  = blockIdx.x * 2;

    if (tid < 144) {
        reinterpret_cast<float4*>(x1s)[tid] =
            reinterpret_cast<const float4*>(x1 + (size_t)z0 * 288)[tid];
        reinterpret_cast<float4*>(x2s)[tid] =
            reinterpret_cast<const float4*>(x2 + (size_t)z0 * 288)[tid];
    }

    alignas(16) float acc[NSLOT];
    #pragma unroll
    for (int s = 0; s < NSLOT; ++s) acc[s] = 0.0f;

    __syncthreads();

    const float* xa = x1s + zg * 288;
    const float* xb = x2s + zg * 288;

    for (int step = 0; step < 8; ++step) {
        const int u = q * 8 + step;

        // ---------- T phase: thread computes T[(q,zg,v=lw)][35] ----------
        float a[9], b[9];
        a[0] = xa[u];
        #pragma unroll
        for (int i = 0; i < 3; ++i) a[1 + i] = xa[32 + u * 3 + i];
        #pragma unroll
        for (int i = 0; i < 5; ++i) a[4 + i] = xa[128 + u * 5 + i];
        b[0] = xb[lw];
        #pragma unroll
        for (int j = 0; j < 3; ++j) b[1 + j] = xb[32 + lw * 3 + j];
        #pragma unroll
        for (int j = 0; j < 5; ++j) b[4 + j] = xb[128 + lw * 5 + j];

        alignas(16) float t[NSLOT];
        #pragma unroll
        for (int s = 0; s < NSLOT; ++s) t[s] = 0.0f;

        t_path<0,0,0,   0,  0>(w3j.c, a, b, t);
        t_path<1,1,0,   1,  1>(w3j.c, a, b, t);
        t_path<2,2,0,  10,  2>(w3j.c, a, b, t);
        t_path<0,1,1,  35,  3>(w3j.c, a, b, t);
        t_path<1,0,1,  44,  6>(w3j.c, a, b, t);
        t_path<1,2,1,  53,  9>(w3j.c, a, b, t);
        t_path<2,1,1,  98, 12>(w3j.c, a, b, t);
        t_path<0,2,2, 143, 15>(w3j.c, a, b, t);
        t_path<1,1,2, 168, 20>(w3j.c, a, b, t);
        t_path<2,0,2, 213, 25>(w3j.c, a, b, t);
        t_path<2,2,2, 238, 30>(w3j.c, a, b, t);

        __syncthreads();  // previous main-phase reads of ldsT done
        {
            float4* dst = reinterpret_cast<float4*>(&ldsT[tid * NSLOT]);
            const float4* src = reinterpret_cast<const float4*>(t);
            #pragma unroll
            for (int r = 0; r < 9; ++r) dst[r] = src[r];
        }
        __syncthreads();

        // ---------- main phase: thread = (q, zg, w=lw) ----------
        const float* wsu = ws + u * 1024 + lw;         // + p*32768 + v*32
        const float* tq  = &ldsT[(q * 64 + zg * 32) * NSLOT];
        #pragma unroll 2
        for (int vv = 0; vv < 32; ++vv) {
            alignas(16) float tl[NSLOT];
            const float4* srow = reinterpret_cast<const float4*>(&tq[vv * NSLOT]);
            #pragma unroll
            for (int r = 0; r < 9; ++r)
                reinterpret_cast<float4*>(tl)[r] = srow[r];
            #pragma unroll
            for (int p = 0; p < 11; ++p) {
                const float wv = wsu[p * 32768 + vv * 32];
                #pragma unroll
                for (int k = 0; k < 5; ++k) {
                    if (k < D3_OF[p]) {
                        const int s = SLOT_OF[p] + k;
                        acc[s] = fmaf(wv, tl[s], acc[s]);
                    }
                }
            }
        }
    }

    // ---------- cross-u-quarter reduction + writeout ----------
    __syncthreads();
    {
        float4* dst = reinterpret_cast<float4*>(&ldsT[tid * NSLOT]);
        const float4* src = reinterpret_cast<const float4*>(acc);
        #pragma unroll
        for (int r = 0; r < 9; ++r) dst[r] = src[r];
    }
    __syncthreads();

    for (int o = tid; o < 576; o += 256) {
        const int zz = (o >= 288) ? 1 : 0;
        const int s  = o - zz * 288;
        int w, k, io;
        if (s < 32)       { io = 0; w = s;             k = 0; }
        else if (s < 128) { io = 1; w = (s - 32) / 3;  k = (s - 32) % 3; }
        else              { io = 2; w = (s - 128) / 5; k = (s - 128) % 5; }
        float val = 0.0f;
        #pragma unroll
        for (int qq = 0; qq < 4; ++qq) {
            const float* pr = &ldsT[((qq * 2 + zz) * 32 + w) * NSLOT];
            if (io == 0)      val += pr[0] + pr[1] + pr[2];
            else if (io == 1) val += pr[3 + k] + pr[6 + k] + pr[9 + k] + pr[12 + k];
            else              val += pr[15 + k] + pr[20 + k] + pr[25 + k] + pr[30 + k];
        }
        out[(size_t)(z0 + zz) * 288 + s] = val;
    }
}

// ======================================================================

extern "C" void kernel_launch(void* const* d_in, const int* in_sizes, int n_in,
                              void* d_out, int out_size, void* d_ws, size_t ws_size,
                              hipStream_t stream) {
    const float* x1 = (const float*)d_in[0];
    const float* x2 = (const float*)d_in[1];
    const float* ws = (const float*)d_in[2];
    float* out = (float*)d_out;

    static const W3JArg arg = build_w3j();  // host-side, computed once

    const int B = in_sizes[0] / 288;        // 2048
    tp_kernel<<<dim3(B / 2), dim3(256), 0, stream>>>(x1, x2, ws, out, arg);
}

// Round 2
// 144.073 us; speedup vs baseline: 5.0282x; 5.0282x over previous
//
#include <hip/hip_runtime.h>
#include <hip/hip_bf16.h>
#include <cmath>
#include <complex>
#include <algorithm>

// ======================================================================
// Host-side exact port of the reference e3nn wigner_3j (unit Frobenius
// norm, real basis, (-1j)^l phase). Computed once, passed by value.
// ======================================================================

typedef std::complex<double> cd;

static double factd(int n) { double r = 1; for (int i = 2; i <= n; ++i) r *= i; return r; }

static double su2_cg(int j1, int m1, int j2, int m2, int j3, int m3) {
    if (m3 != m1 + m2) return 0.0;
    int vmin = std::max(std::max(-j1 + j2 + m3, -j1 + m1), 0);
    int vmax = std::min(std::min(j2 + j3 + m1, j3 - j1 + j2), j3 + m3);
    double C = std::sqrt((2.0 * j3 + 1.0) *
        (factd(j3 + j1 - j2) * factd(j3 - j1 + j2) * factd(j1 + j2 - j3) *
         factd(j3 + m3) * factd(j3 - m3)) /
        (factd(j1 + j2 + j3 + 1) * factd(j1 - m1) * factd(j1 + m1) *
         factd(j2 - m2) * factd(j2 + m2)));
    double S = 0.0;
    for (int v = vmin; v <= vmax; ++v) {
        double sgn = ((v + j2 + m2) & 1) ? -1.0 : 1.0;
        S += sgn * (factd(j2 + j3 + m1 - v) * factd(j1 - m1 + v)) /
             (factd(v) * factd(j3 - j1 + j2 - v) * factd(j3 + m3 - v) *
              factd(v + j1 - j2 - m3));
    }
    return C * S;
}

static void qmat(int l, cd* q) {
    int n = 2 * l + 1;
    for (int i = 0; i < n * n; ++i) q[i] = cd(0, 0);
    const double s = 1.0 / std::sqrt(2.0);
    for (int m = -l; m < 0; ++m) {
        q[(l + m) * n + (l - m)] = cd(s, 0);
        q[(l + m) * n + (l + m)] = cd(0, -s);
    }
    q[l * n + l] = cd(1, 0);
    for (int m = 1; m <= l; ++m) {
        double sg = (m & 1) ? -1.0 : 1.0;
        q[(l + m) * n + (l + m)] = cd(sg * s, 0);
        q[(l + m) * n + (l - m)] = cd(0, sg * s);
    }
    cd ph(1, 0);
    for (int t = 0; t < l; ++t) ph *= cd(0, -1);
    for (int i = 0; i < n * n; ++i) q[i] *= ph;
}

static void wigner3j_dense(int l1, int l2, int l3, float* outp) {
    int n1 = 2 * l1 + 1, n2 = 2 * l2 + 1, n3 = 2 * l3 + 1;
    double cg[125];
    for (int i = 0; i < n1 * n2 * n3; ++i) cg[i] = 0.0;
    for (int m1 = -l1; m1 <= l1; ++m1)
        for (int m2 = -l2; m2 <= l2; ++m2) {
            int m3 = m1 + m2;
            if (std::abs(m3) <= l3)
                cg[((l1 + m1) * n2 + (l2 + m2)) * n3 + (l3 + m3)] =
                    su2_cg(l1, m1, l2, m2, l3, m3);
        }
    cd q1[25], q2[25], q3[25];
    qmat(l1, q1); qmat(l2, q2); qmat(l3, q3);
    double C[125]; double norm2 = 0.0;
    for (int j = 0; j < n1; ++j)
        for (int l = 0; l < n2; ++l)
            for (int m = 0; m < n3; ++m) {
                cd sum(0, 0);
                for (int i = 0; i < n1; ++i)
                    for (int k = 0; k < n2; ++k)
                        for (int n = 0; n < n3; ++n) {
                            double g = cg[(i * n2 + k) * n3 + n];
                            if (g != 0.0)
                                sum += q1[i * n1 + j] * q2[k * n2 + l] *
                                       std::conj(q3[n * n3 + m]) * g;
                        }
                C[(j * n2 + l) * n3 + m] = sum.real();
                norm2 += sum.real() * sum.real();
            }
    double inv = 1.0 / std::sqrt(norm2);
    for (int t = 0; t < n1 * n2 * n3; ++t) outp[t] = (float)(C[t] * inv);
}

struct W3JArg { float c[363]; };

static W3JArg build_w3j() {
    W3JArg arg;
    struct P { int l1, l2, lo, coff; double alpha; };
    const P ps[11] = {
        {0,0,0,   0, std::sqrt(1.0/3072.0)},
        {1,1,0,   1, std::sqrt(1.0/3072.0)},
        {2,2,0,  10, std::sqrt(1.0/3072.0)},
        {0,1,1,  35, std::sqrt(3.0/4096.0)},
        {1,0,1,  44, std::sqrt(3.0/4096.0)},
        {1,2,1,  53, std::sqrt(3.0/4096.0)},
        {2,1,1,  98, std::sqrt(3.0/4096.0)},
        {0,2,2, 143, std::sqrt(5.0/4096.0)},
        {1,1,2, 168, std::sqrt(5.0/4096.0)},
        {2,0,2, 213, std::sqrt(5.0/4096.0)},
        {2,2,2, 238, std::sqrt(5.0/4096.0)}
    };
    for (int pi = 0; pi < 11; ++pi) {
        const P& p = ps[pi];
        float tmp[125];
        wigner3j_dense(p.l1, p.l2, p.lo, tmp);
        int n = (2*p.l1+1) * (2*p.l2+1) * (2*p.lo+1);
        for (int t = 0; t < n; ++t) arg.c[p.coff + t] = (float)(tmp[t] * p.alpha);
    }
    return arg;
}

// ======================================================================
// Device
// ======================================================================

typedef __attribute__((ext_vector_type(8))) short short8;
typedef __attribute__((ext_vector_type(4))) float f32x4;

__device__ __forceinline__ unsigned short f2bf_bits(float f) {
    __hip_bfloat16 h = __float2bfloat16(f);
    unsigned short u; __builtin_memcpy(&u, &h, 2); return u;
}

__device__ __forceinline__ unsigned pack2(float lo, float hi) {
    return (unsigned)f2bf_bits(lo) | ((unsigned)f2bf_bits(hi) << 16);
}

// Dense per-path T build: t[SLOT + k*STRIDE] += C[i,j,k] * a[i]*b[j]
template<int L1, int L2, int LO, int COFF, int SLOT, int STRIDE>
__device__ __forceinline__ void t_path(const float* __restrict__ c,
                                       const float* a, const float* b, float* t) {
    constexpr int D1 = 2*L1+1, D2 = 2*L2+1, D3 = 2*LO+1;
    constexpr int A1 = (L1==0)?0:(L1==1)?1:4;
    constexpr int A2 = (L2==0)?0:(L2==1)?1:4;
    #pragma unroll
    for (int i = 0; i < D1; ++i)
        #pragma unroll
        for (int j = 0; j < D2; ++j) {
            float prod = a[A1+i] * b[A2+j];
            #pragma unroll
            for (int k = 0; k < D3; ++k)
                t[SLOT + k*STRIDE] = fmaf(c[COFF + (i*D2+j)*D3 + k], prod, t[SLOT + k*STRIDE]);
        }
}

// Slot layout (target-major so same-output slots chain into one acc):
//  io0: s0=p0, s1=p1, s2=p2                        (k=0)
//  io1: s=3+k*4+m, path p3+m, k=0..2               (slots 3..14)
//  io2: s=15+k*4+m, path p7+m, k=0..4              (slots 15..34)
__device__ __forceinline__ void build_t(const float* __restrict__ c,
                                        const float* a, const float* b, float* t) {
    #pragma unroll
    for (int s = 0; s < 35; ++s) t[s] = 0.0f;
    t_path<0,0,0,   0,  0, 1>(c, a, b, t);
    t_path<1,1,0,   1,  1, 1>(c, a, b, t);
    t_path<2,2,0,  10,  2, 1>(c, a, b, t);
    t_path<0,1,1,  35,  3, 4>(c, a, b, t);
    t_path<1,0,1,  44,  4, 4>(c, a, b, t);
    t_path<1,2,1,  53,  5, 4>(c, a, b, t);
    t_path<2,1,1,  98,  6, 4>(c, a, b, t);
    t_path<0,2,2, 143, 15, 4>(c, a, b, t);
    t_path<1,1,2, 168, 16, 4>(c, a, b, t);
    t_path<2,0,2, 213, 17, 4>(c, a, b, t);
    t_path<2,2,2, 238, 18, 4>(c, a, b, t);
}

// B fragment: ws_p[u][v(K)][w(N)] -> lane(n=l&15 -> w, k=(l>>4)*8+j -> v)
template<bool USE_WST>
__device__ __forceinline__ short8 load_bfrag(const float* __restrict__ ws,
                                             const unsigned short* __restrict__ wsT,
                                             int p, int u, int w, int vbase) {
    if constexpr (USE_WST) {
        return *(const short8*)(wsT + (((size_t)(p*32+u)*32 + w)*32 + vbase));
    } else {
        short8 r;
        #pragma unroll
        for (int j = 0; j < 8; ++j) {
            float f = ws[((size_t)(p*32+u)*32 + (vbase+j))*32 + w];
            r[j] = (short)f2bf_bits(f);
        }
        return r;
    }
}

// ws prep: wsT[p][u][w][v] bf16  <-  ws[p][u][v][w] fp32 (one-time, tiny)
__global__ void ws_prep(const float* __restrict__ ws, unsigned short* __restrict__ wsT) {
    __shared__ float tile[32][33];
    const int pu = blockIdx.x, tid = threadIdx.x;
    const float4 f = ((const float4*)(ws + (size_t)pu * 1024))[tid];
    const int v = tid >> 3, w0 = (tid & 7) * 4;
    tile[v][w0+0] = f.x; tile[v][w0+1] = f.y; tile[v][w0+2] = f.z; tile[v][w0+3] = f.w;
    __syncthreads();
    const int w = tid >> 3, vB = (tid & 7) * 4;
    ushort4 o;
    o.x = f2bf_bits(tile[vB+0][w]); o.y = f2bf_bits(tile[vB+1][w]);
    o.z = f2bf_bits(tile[vB+2][w]); o.w = f2bf_bits(tile[vB+3][w]);
    *(ushort4*)(wsT + (size_t)pu * 1024 + tid * 4) = o;
}

// Main kernel: block = 16 z x 8 u, 4 waves = (kh: slot-half) x (nt: w-half)
template<bool USE_WST>
__launch_bounds__(256, 2)
__global__ void tp_mfma(const float* __restrict__ x1, const float* __restrict__ x2,
                        const float* __restrict__ ws, const unsigned short* __restrict__ wsT,
                        float* __restrict__ out, W3JArg w3j) {
    __shared__ unsigned shT[35 * 256];   // T[s][z(16)][vpair(16)] packed bf16x2
    __shared__ float x1s[16 * 292];      // stride 292: 4-float4-aligned, banks shift by 4/z
    __shared__ float x2s[16 * 292];

    const int tid = threadIdx.x;
    const int l = tid & 63, wv = tid >> 6, kh = wv & 1, nt = wv >> 1;
    const int zb = blockIdx.x >> 2, ug = blockIdx.x & 3;
    const int z0 = zb * 16, u0 = ug * 8;

    for (int i = tid; i < 16 * 72; i += 256) {
        int row = i / 72, c4 = i - row * 72;
        ((float4*)(x1s + row * 292))[c4] = ((const float4*)(x1 + (size_t)(z0 + row) * 288))[c4];
        ((float4*)(x2s + row * 292))[c4] = ((const float4*)(x2 + (size_t)(z0 + row) * 288))[c4];
    }
    __syncthreads();

    // T-build thread mapping: z = tid>>4, v-pair = tid&15 (v = 2vp, 2vp+1)
    const int tz = tid >> 4, vp = tid & 15, v0 = vp * 2;
    float b0[9], b1[9];
    {
        const float* xr = x2s + tz * 292;
        b0[0] = xr[v0]; b1[0] = xr[v0 + 1];
        #pragma unroll
        for (int j = 0; j < 3; ++j) { b0[1+j] = xr[32 + v0*3 + j]; b1[1+j] = xr[32 + (v0+1)*3 + j]; }
        #pragma unroll
        for (int j = 0; j < 5; ++j) { b0[4+j] = xr[128 + v0*5 + j]; b1[4+j] = xr[128 + (v0+1)*5 + j]; }
    }

    f32x4 acc[5];
    #pragma unroll
    for (int i = 0; i < 5; ++i) acc[i] = (f32x4)(0.0f);

    const int w = (l & 15) + nt * 16;        // N index (output mul w)
    const int vb = (l >> 4) * 8;             // K base (v)
    const unsigned* tbase = shT + (l & 15) * 16 + (l >> 4) * 4;  // A-frag base

    for (int ui = 0; ui < 8; ++ui) {
        const int u = u0 + ui;

        // B fragments issued early -> latency hides under T-build VALU
        short8 bf[7];
        if (kh == 0) {
            #pragma unroll
            for (int p = 0; p < 7; ++p) bf[p] = load_bfrag<USE_WST>(ws, wsT, p, u, w, vb);
        } else {
            #pragma unroll
            for (int p = 0; p < 4; ++p) bf[p] = load_bfrag<USE_WST>(ws, wsT, 7 + p, u, w, vb);
        }

        // ---- T build (all 256 threads) ----
        float a[9];
        {
            const float* xr = x1s + tz * 292;
            a[0] = xr[u];
            #pragma unroll
            for (int i = 0; i < 3; ++i) a[1+i] = xr[32 + u*3 + i];
            #pragma unroll
            for (int i = 0; i < 5; ++i) a[4+i] = xr[128 + u*5 + i];
        }
        float t0[35], t1[35];
        build_t(w3j.c, a, b0, t0);
        build_t(w3j.c, a, b1, t1);

        __syncthreads();   // prior MFMA reads of shT complete
        {
            unsigned* dst = shT + tz * 16 + vp;
            #pragma unroll
            for (int s = 0; s < 35; ++s) dst[s * 256] = pack2(t0[s], t1[s]);
        }
        __syncthreads();

        // ---- MFMA phase (wave-specialized; same-target slots chain one acc) ----
        if (kh == 0) {
            #pragma unroll
            for (int m = 0; m < 3; ++m) {
                short8 af = *(const short8*)(tbase + m * 256);
                acc[0] = __builtin_amdgcn_mfma_f32_16x16x32_bf16(af, bf[m], acc[0], 0, 0, 0);
            }
            #pragma unroll
            for (int g = 0; g < 3; ++g)
                #pragma unroll
                for (int m = 0; m < 4; ++m) {
                    short8 af = *(const short8*)(tbase + (3 + g*4 + m) * 256);
                    acc[1+g] = __builtin_amdgcn_mfma_f32_16x16x32_bf16(af, bf[3+m], acc[1+g], 0, 0, 0);
                }
        } else {
            #pragma unroll
            for (int g = 0; g < 5; ++g)
                #pragma unroll
                for (int m = 0; m < 4; ++m) {
                    short8 af = *(const short8*)(tbase + (15 + g*4 + m) * 256);
                    acc[g] = __builtin_amdgcn_mfma_f32_16x16x32_bf16(af, bf[m], acc[g], 0, 0, 0);
                }
        }
    }

    // ---- epilogue: D row = z0 + (l>>4)*4 + r, col = w ----
    const int zr = z0 + ((l >> 4) << 2);
    if (kh == 0) {
        #pragma unroll
        for (int r = 0; r < 4; ++r)
            atomicAdd(&out[(size_t)(zr + r) * 288 + w], acc[0][r]);
        #pragma unroll
        for (int k = 0; k < 3; ++k)
            #pragma unroll
            for (int r = 0; r < 4; ++r)
                atomicAdd(&out[(size_t)(zr + r) * 288 + 32 + w*3 + k], acc[1+k][r]);
    } else {
        #pragma unroll
        for (int k = 0; k < 5; ++k)
            #pragma unroll
            for (int r = 0; r < 4; ++r)
                atomicAdd(&out[(size_t)(zr + r) * 288 + 128 + w*5 + k], acc[k][r]);
    }
}

// ======================================================================

extern "C" void kernel_launch(void* const* d_in, const int* in_sizes, int n_in,
                              void* d_out, int out_size, void* d_ws, size_t ws_size,
                              hipStream_t stream) {
    const float* x1 = (const float*)d_in[0];
    const float* x2 = (const float*)d_in[1];
    const float* ws = (const float*)d_in[2];
    float* out = (float*)d_out;

    static const W3JArg arg = build_w3j();

    const int B = in_sizes[0] / 288;          // 2048
    const int grid = (B / 16) * 4;            // z-blocks x 4 u-groups

    hipMemsetAsync(d_out, 0, (size_t)out_size * sizeof(float), stream);

    const size_t wst_bytes = (size_t)11 * 32 * 32 * 32 * 2;
    unsigned short* wsT = (unsigned short*)d_ws;
    if (ws_size >= wst_bytes) {
        ws_prep<<<dim3(11 * 32), dim3(256), 0, stream>>>(ws, wsT);
        tp_mfma<true><<<dim3(grid), dim3(256), 0, stream>>>(x1, x2, ws, wsT, out, arg);
    } else {
        tp_mfma<false><<<dim3(grid), dim3(256), 0, stream>>>(x1, x2, ws, wsT, out, arg);
    }
}

// Round 3
// 106.532 us; speedup vs baseline: 6.8001x; 1.3524x over previous
//
#include <hip/hip_runtime.h>
#include <hip/hip_bf16.h>
#include <cmath>
#include <complex>
#include <algorithm>

// ======================================================================
// Host-side exact port of the reference e3nn wigner_3j (unit Frobenius
// norm, real basis, (-1j)^l phase). Computed once, passed by value.
// ======================================================================

typedef std::complex<double> cd;

static double factd(int n) { double r = 1; for (int i = 2; i <= n; ++i) r *= i; return r; }

static double su2_cg(int j1, int m1, int j2, int m2, int j3, int m3) {
    if (m3 != m1 + m2) return 0.0;
    int vmin = std::max(std::max(-j1 + j2 + m3, -j1 + m1), 0);
    int vmax = std::min(std::min(j2 + j3 + m1, j3 - j1 + j2), j3 + m3);
    double C = std::sqrt((2.0 * j3 + 1.0) *
        (factd(j3 + j1 - j2) * factd(j3 - j1 + j2) * factd(j1 + j2 - j3) *
         factd(j3 + m3) * factd(j3 - m3)) /
        (factd(j1 + j2 + j3 + 1) * factd(j1 - m1) * factd(j1 + m1) *
         factd(j2 - m2) * factd(j2 + m2)));
    double S = 0.0;
    for (int v = vmin; v <= vmax; ++v) {
        double sgn = ((v + j2 + m2) & 1) ? -1.0 : 1.0;
        S += sgn * (factd(j2 + j3 + m1 - v) * factd(j1 - m1 + v)) /
             (factd(v) * factd(j3 - j1 + j2 - v) * factd(j3 + m3 - v) *
              factd(v + j1 - j2 - m3));
    }
    return C * S;
}

static void qmat(int l, cd* q) {
    int n = 2 * l + 1;
    for (int i = 0; i < n * n; ++i) q[i] = cd(0, 0);
    const double s = 1.0 / std::sqrt(2.0);
    for (int m = -l; m < 0; ++m) {
        q[(l + m) * n + (l - m)] = cd(s, 0);
        q[(l + m) * n + (l + m)] = cd(0, -s);
    }
    q[l * n + l] = cd(1, 0);
    for (int m = 1; m <= l; ++m) {
        double sg = (m & 1) ? -1.0 : 1.0;
        q[(l + m) * n + (l + m)] = cd(sg * s, 0);
        q[(l + m) * n + (l - m)] = cd(0, sg * s);
    }
    cd ph(1, 0);
    for (int t = 0; t < l; ++t) ph *= cd(0, -1);
    for (int i = 0; i < n * n; ++i) q[i] *= ph;
}

static void wigner3j_dense(int l1, int l2, int l3, double* outp) {
    int n1 = 2 * l1 + 1, n2 = 2 * l2 + 1, n3 = 2 * l3 + 1;
    double cg[125];
    for (int i = 0; i < n1 * n2 * n3; ++i) cg[i] = 0.0;
    for (int m1 = -l1; m1 <= l1; ++m1)
        for (int m2 = -l2; m2 <= l2; ++m2) {
            int m3 = m1 + m2;
            if (std::abs(m3) <= l3)
                cg[((l1 + m1) * n2 + (l2 + m2)) * n3 + (l3 + m3)] =
                    su2_cg(l1, m1, l2, m2, l3, m3);
        }
    cd q1[25], q2[25], q3[25];
    qmat(l1, q1); qmat(l2, q2); qmat(l3, q3);
    double norm2 = 0.0;
    for (int j = 0; j < n1; ++j)
        for (int l = 0; l < n2; ++l)
            for (int m = 0; m < n3; ++m) {
                cd sum(0, 0);
                for (int i = 0; i < n1; ++i)
                    for (int k = 0; k < n2; ++k)
                        for (int n = 0; n < n3; ++n) {
                            double g = cg[(i * n2 + k) * n3 + n];
                            if (g != 0.0)
                                sum += q1[i * n1 + j] * q2[k * n2 + l] *
                                       std::conj(q3[n * n3 + m]) * g;
                        }
                outp[(j * n2 + l) * n3 + m] = sum.real();
                norm2 += sum.real() * sum.real();
            }
    double inv = 1.0 / std::sqrt(norm2);
    for (int t = 0; t < n1 * n2 * n3; ++t) outp[t] *= inv;
}

// ======================================================================
// Sparsity pattern of the real-basis w3j (structural nonzeros).
// Selection rules: |m3| in {|m1|+|m2|, ||m1|-|m2||} and even # of
// negative-m components. Shared by host fill and device unrolled code.
// ======================================================================

struct E3 { unsigned char i, j, k; };

constexpr E3 PAT_P0[1]  = {{0,0,0}};
constexpr E3 PAT_P1[3]  = {{0,0,0},{1,1,0},{2,2,0}};
constexpr E3 PAT_P2[5]  = {{0,0,0},{1,1,0},{2,2,0},{3,3,0},{4,4,0}};
constexpr E3 PAT_P3[3]  = {{0,0,0},{0,1,1},{0,2,2}};
constexpr E3 PAT_P4[3]  = {{0,0,0},{1,0,1},{2,0,2}};
constexpr E3 PAT_P5[11] = {{1,2,1},{1,3,2},{1,1,0},{2,2,2},{0,2,0},{2,3,1},
                           {0,1,1},{2,4,2},{0,0,2},{2,0,0},{0,4,0}};
constexpr E3 PAT_P6[11] = {{2,1,1},{2,2,2},{2,0,0},{3,1,2},{1,1,0},{3,2,1},
                           {1,0,1},{4,2,2},{0,0,2},{4,0,0},{0,2,0}};
constexpr E3 PAT_P7[5]  = {{0,0,0},{0,1,1},{0,2,2},{0,3,3},{0,4,4}};
constexpr E3 PAT_P8[11] = {{1,1,2},{1,2,3},{1,0,1},{2,1,3},{0,1,1},{2,2,2},
                           {0,0,2},{2,2,4},{0,0,4},{2,0,0},{0,2,0}};
constexpr E3 PAT_P9[5]  = {{0,0,0},{1,0,1},{2,0,2},{3,0,3},{4,0,4}};
constexpr E3 PAT_P10[25]= {{2,2,2},{2,3,3},{2,1,1},{2,4,4},{2,0,0},{3,2,3},
                           {1,2,1},{3,3,2},{1,1,2},{3,3,4},{1,1,4},{3,1,0},
                           {1,3,0},{3,4,3},{1,0,3},{3,0,1},{1,4,1},{4,2,4},
                           {0,2,0},{4,3,3},{0,1,3},{4,1,1},{0,3,1},{4,4,2},
                           {0,0,2}};

// value-array offsets per path: sizes 1,3,5,3,3,11,11,5,11,5,25 -> total 83
constexpr int OFF_P[11] = {0, 1, 4, 9, 12, 15, 26, 37, 42, 53, 58};

struct W3JArg { float c[83]; };

static W3JArg build_w3j_sparse() {
    struct PD { const E3* pat; int ne; int l1, l2, lo; double alpha; };
    const double a0 = std::sqrt(1.0/3072.0), a1 = std::sqrt(3.0/4096.0),
                 a2 = std::sqrt(5.0/4096.0);
    const PD pd[11] = {
        {PAT_P0, 1, 0,0,0, a0}, {PAT_P1, 3, 1,1,0, a0}, {PAT_P2, 5, 2,2,0, a0},
        {PAT_P3, 3, 0,1,1, a1}, {PAT_P4, 3, 1,0,1, a1}, {PAT_P5,11, 1,2,1, a1},
        {PAT_P6,11, 2,1,1, a1}, {PAT_P7, 5, 0,2,2, a2}, {PAT_P8,11, 1,1,2, a2},
        {PAT_P9, 5, 2,0,2, a2}, {PAT_P10,25,2,2,2, a2}
    };
    W3JArg arg;
    for (int p = 0; p < 11; ++p) {
        double dense[125];
        wigner3j_dense(pd[p].l1, pd[p].l2, pd[p].lo, dense);
        int n2 = 2*pd[p].l2+1, n3 = 2*pd[p].lo+1;
        for (int e = 0; e < pd[p].ne; ++e) {
            const E3& t = pd[p].pat[e];
            arg.c[OFF_P[p] + e] =
                (float)(dense[(t.i * n2 + t.j) * n3 + t.k] * pd[p].alpha);
        }
    }
    return arg;
}

// ======================================================================
// Device
// ======================================================================

typedef __attribute__((ext_vector_type(8))) short short8;
typedef __attribute__((ext_vector_type(4))) float f32x4;

__device__ __forceinline__ unsigned short f2bf_bits(float f) {
    __hip_bfloat16 h = __float2bfloat16(f);
    unsigned short u; __builtin_memcpy(&u, &h, 2); return u;
}

// One path: accumulate its nnz entries into t0/t1[D3], pack, store to shT.
// dst is the thread's swizzled base word in shT; slot s lives at dst[s*256].
template<int NE, int A1, int A2, int D3, int SBASE, int SSTR>
__device__ __forceinline__ void do_path(const E3 (&pat)[NE],
                                        const float* __restrict__ cs,
                                        const float* a, const float* b0,
                                        const float* b1,
                                        unsigned* __restrict__ dst) {
    float t0[D3], t1[D3];
    #pragma unroll
    for (int k = 0; k < D3; ++k) { t0[k] = 0.0f; t1[k] = 0.0f; }
    #pragma unroll
    for (int e = 0; e < NE; ++e) {
        const float c = cs[e];
        const float av = a[A1 + pat[e].i];
        const int k = pat[e].k;
        t0[k] = fmaf(c, av * b0[A2 + pat[e].j], t0[k]);
        t1[k] = fmaf(c, av * b1[A2 + pat[e].j], t1[k]);
    }
    #pragma unroll
    for (int k = 0; k < D3; ++k) {
        float2 f2; f2.x = t0[k]; f2.y = t1[k];
        __hip_bfloat162 pk = __float22bfloat162_rn(f2);
        unsigned u; __builtin_memcpy(&u, &pk, 4);
        dst[(SBASE + k * SSTR) * 256] = u;
    }
}

__device__ __forceinline__ void build_all(const float* __restrict__ cs,
                                          const float* a, const float* b0,
                                          const float* b1,
                                          unsigned* __restrict__ dst) {
    do_path< 1,0,0,1, 0,1>(PAT_P0,  cs +  0, a, b0, b1, dst);
    do_path< 3,1,1,1, 1,1>(PAT_P1,  cs +  1, a, b0, b1, dst);
    do_path< 5,4,4,1, 2,1>(PAT_P2,  cs +  4, a, b0, b1, dst);
    do_path< 3,0,1,3, 3,4>(PAT_P3,  cs +  9, a, b0, b1, dst);
    do_path< 3,1,0,3, 4,4>(PAT_P4,  cs + 12, a, b0, b1, dst);
    do_path<11,1,4,3, 5,4>(PAT_P5,  cs + 15, a, b0, b1, dst);
    do_path<11,4,1,3, 6,4>(PAT_P6,  cs + 26, a, b0, b1, dst);
    do_path< 5,0,4,5,15,4>(PAT_P7,  cs + 37, a, b0, b1, dst);
    do_path<11,1,1,5,16,4>(PAT_P8,  cs + 42, a, b0, b1, dst);
    do_path< 5,4,0,5,17,4>(PAT_P9,  cs + 53, a, b0, b1, dst);
    do_path<25,4,4,5,18,4>(PAT_P10, cs + 58, a, b0, b1, dst);
}

// B fragment: wsT[p][u][w][v] bf16; lane: n = l&15 -> w, k = (l>>4)*8+j -> v
template<bool USE_WST>
__device__ __forceinline__ short8 load_bfrag(const float* __restrict__ ws,
                                             const unsigned short* __restrict__ wsT,
                                             int p, int u, int w, int vbase) {
    if constexpr (USE_WST) {
        return *(const short8*)(wsT + (((size_t)(p*32+u)*32 + w)*32 + vbase));
    } else {
        short8 r;
        #pragma unroll
        for (int j = 0; j < 8; ++j) {
            float f = ws[((size_t)(p*32+u)*32 + (vbase+j))*32 + w];
            r[j] = (short)f2bf_bits(f);
        }
        return r;
    }
}

// ws prep: wsT[p][u][w][v] bf16 <- ws[p][u][v][w] fp32, plus zero `out`
__global__ void ws_prep(const float* __restrict__ ws,
                        unsigned short* __restrict__ wsT,
                        float* __restrict__ out) {
    __shared__ float tile[32][33];
    const int pu = blockIdx.x, tid = threadIdx.x;
    const float4 f = ((const float4*)(ws + (size_t)pu * 1024))[tid];
    const int v = tid >> 3, w0 = (tid & 7) * 4;
    tile[v][w0+0] = f.x; tile[v][w0+1] = f.y; tile[v][w0+2] = f.z; tile[v][w0+3] = f.w;

    // zero the output (2048*288 floats = 147456 float4s) while we wait
    float4 z4; z4.x = z4.y = z4.z = z4.w = 0.0f;
    for (int i = blockIdx.x * 256 + tid; i < 147456; i += 352 * 256)
        ((float4*)out)[i] = z4;

    __syncthreads();
    const int w = tid >> 3, vB = (tid & 7) * 4;
    ushort4 o;
    o.x = f2bf_bits(tile[vB+0][w]); o.y = f2bf_bits(tile[vB+1][w]);
    o.z = f2bf_bits(tile[vB+2][w]); o.w = f2bf_bits(tile[vB+3][w]);
    *(ushort4*)(wsT + (size_t)pu * 1024 + tid * 4) = o;
}

// Main kernel: block = 256 = 16 z x 16 v-pairs (T build) = 4 waves
// (kh: slot-group) x (nt: w-half) for MFMA. Grid = (B/16) z-tiles x 4 u-groups.
template<bool USE_WST>
__launch_bounds__(256, 3)
__global__ void tp_mfma(const float* __restrict__ x1, const float* __restrict__ x2,
                        const float* __restrict__ ws, const unsigned short* __restrict__ wsT,
                        float* __restrict__ out, W3JArg w3j) {
    __shared__ unsigned shT[35 * 256];  // T[s][z(16)][v-word(16)], col-swizzled
    __shared__ float x1s[16 * 288];

    const int tid = threadIdx.x;
    const int l = tid & 63, wv = tid >> 6, kh = wv & 1, nt = wv >> 1;
    const int z0 = (blockIdx.x >> 2) * 16, u0 = (blockIdx.x & 3) * 8;

    for (int i = tid; i < 16 * 72; i += 256)
        ((float4*)x1s)[i] = ((const float4*)(x1 + (size_t)z0 * 288))[i];

    // T-build mapping: z = tid>>4, v-pair = tid&15 (v = 2vp, 2vp+1)
    const int tz = tid >> 4, vp = tid & 15, v0 = vp * 2;

    // b0/b1 straight from global (one-time, L2-hot)
    float b0[9], b1[9];
    {
        const float* xr = x2 + (size_t)(z0 + tz) * 288;
        b0[0] = xr[v0]; b1[0] = xr[v0 + 1];
        #pragma unroll
        for (int j = 0; j < 3; ++j) { b0[1+j] = xr[32 + v0*3 + j]; b1[1+j] = xr[32 + (v0+1)*3 + j]; }
        #pragma unroll
        for (int j = 0; j < 5; ++j) { b0[4+j] = xr[128 + v0*5 + j]; b1[4+j] = xr[128 + (v0+1)*5 + j]; }
    }

    // swizzled store base: word = tz*16 + (vp&3) + (((vp>>2)+(tz>>1))&3)*4
    unsigned* dstT = shT + tz * 16 + (vp & 3) + ((((vp >> 2) + (tz >> 1)) & 3) << 2);
    // swizzled read base: lane z = l&15, v-group = l>>4
    const unsigned* tbase = shT + (l & 15) * 16 +
                            ((((l >> 4) + ((l & 15) >> 1)) & 3) << 2);

    const int w  = (l & 15) + nt * 16;   // N index (output mul w)
    const int vb = (l >> 4) * 8;         // K base (v)

    f32x4 acc[5];
    #pragma unroll
    for (int i = 0; i < 5; ++i) acc[i] = (f32x4)(0.0f);

    __syncthreads();

    for (int ui = 0; ui < 8; ++ui) {
        const int u = u0 + ui;

        // B fragments issued early -> latency hides under barrier + build
        short8 bf[7];
        if (kh == 0) {
            #pragma unroll
            for (int p = 0; p < 7; ++p) bf[p] = load_bfrag<USE_WST>(ws, wsT, p, u, w, vb);
        } else {
            #pragma unroll
            for (int p = 0; p < 4; ++p) bf[p] = load_bfrag<USE_WST>(ws, wsT, 7 + p, u, w, vb);
        }

        float a[9];
        {
            const float* xr = x1s + tz * 288;
            a[0] = xr[u];
            #pragma unroll
            for (int i = 0; i < 3; ++i) a[1+i] = xr[32 + u*3 + i];
            #pragma unroll
            for (int i = 0; i < 5; ++i) a[4+i] = xr[128 + u*5 + i];
        }

        __syncthreads();   // prior MFMA reads of shT complete
        build_all(w3j.c, a, b0, b1, dstT);   // sparse build + pack + store
        __syncthreads();

        // ---- MFMA phase (wave-specialized; same-target slots chain one acc) ----
        if (kh == 0) {
            #pragma unroll
            for (int m = 0; m < 3; ++m) {
                short8 af = *(const short8*)(tbase + m * 256);
                acc[0] = __builtin_amdgcn_mfma_f32_16x16x32_bf16(af, bf[m], acc[0], 0, 0, 0);
            }
            #pragma unroll
            for (int g = 0; g < 3; ++g)
                #pragma unroll
                for (int m = 0; m < 4; ++m) {
                    short8 af = *(const short8*)(tbase + (3 + g*4 + m) * 256);
                    acc[1+g] = __builtin_amdgcn_mfma_f32_16x16x32_bf16(af, bf[3+m], acc[1+g], 0, 0, 0);
                }
        } else {
            #pragma unroll
            for (int g = 0; g < 5; ++g)
                #pragma unroll
                for (int m = 0; m < 4; ++m) {
                    short8 af = *(const short8*)(tbase + (15 + g*4 + m) * 256);
                    acc[g] = __builtin_amdgcn_mfma_f32_16x16x32_bf16(af, bf[m], acc[g], 0, 0, 0);
                }
        }
    }

    // ---- epilogue: D row = z0 + (l>>4)*4 + r, col = w ----
    const int zr = z0 + ((l >> 4) << 2);
    if (kh == 0) {
        #pragma unroll
        for (int r = 0; r < 4; ++r)
            atomicAdd(&out[(size_t)(zr + r) * 288 + w], acc[0][r]);
        #pragma unroll
        for (int k = 0; k < 3; ++k)
            #pragma unroll
            for (int r = 0; r < 4; ++r)
                atomicAdd(&out[(size_t)(zr + r) * 288 + 32 + w*3 + k], acc[1+k][r]);
    } else {
        #pragma unroll
        for (int k = 0; k < 5; ++k)
            #pragma unroll
            for (int r = 0; r < 4; ++r)
                atomicAdd(&out[(size_t)(zr + r) * 288 + 128 + w*5 + k], acc[k][r]);
    }
}

// ======================================================================

extern "C" void kernel_launch(void* const* d_in, const int* in_sizes, int n_in,
                              void* d_out, int out_size, void* d_ws, size_t ws_size,
                              hipStream_t stream) {
    const float* x1 = (const float*)d_in[0];
    const float* x2 = (const float*)d_in[1];
    const float* ws = (const float*)d_in[2];
    float* out = (float*)d_out;

    static const W3JArg arg = build_w3j_sparse();

    const int B = in_sizes[0] / 288;          // 2048
    const int grid = (B / 16) * 4;            // z-blocks x 4 u-groups

    const size_t wst_bytes = (size_t)11 * 32 * 32 * 32 * 2;
    unsigned short* wsT = (unsigned short*)d_ws;
    if (ws_size >= wst_bytes) {
        ws_prep<<<dim3(11 * 32), dim3(256), 0, stream>>>(ws, wsT, out);
        tp_mfma<true><<<dim3(grid), dim3(256), 0, stream>>>(x1, x2, ws, wsT, out, arg);
    } else {
        hipMemsetAsync(out, 0, (size_t)out_size * sizeof(float), stream);
        tp_mfma<false><<<dim3(grid), dim3(256), 0, stream>>>(x1, x2, ws, wsT, out, arg);
    }
}